// Round 2
// baseline (191.818 us; speedup 1.0000x reference)
//
#include <hip/hip_runtime.h>

// RandomSelfAttention: B=2, S=4096, S2=2048, NH=8, H=64, NKEYS=64
// q:(B,S2,NH,H) f32, k/v:(B,S,NH,H) f32, idx:(B,S2,NKEYS) int
// out z:(B,S2,NH,H) f32
//
// One wave per (b,q,n) unit. Phase1: lane=key slot, per-lane float4 row reads
// + LDS-broadcast q. Softmax via shfl_xor butterfly. Phase2: lane=h,
// coalesced v-row reads, p/offsets broadcast from LDS.
// Block swizzle: blockIdx%16 = (b,n) combo so each XCD's L2 sees a ~4MB
// working set (k+v slices for 2 combos).

#define BB 2
#define SS 4096
#define S2V 2048
#define NHV 8
#define HV 64
#define NKV 64

__global__ __launch_bounds__(256, 4)
void rsa_kernel(const float* __restrict__ q, const float* __restrict__ k,
                const float* __restrict__ v, const int* __restrict__ idx,
                float* __restrict__ out) {
    const int lane = threadIdx.x & 63;
    const int w    = threadIdx.x >> 6;
    const int bi   = blockIdx.x;

    // combo = b*NH + n in [0,16); qi grouped 4-per-block
    const int combo = bi & 15;
    const int b     = combo >> 3;
    const int n     = combo & 7;
    const int qi    = ((bi >> 4) << 2) + w;

    __shared__ float sh_q[4][HV];
    __shared__ float sh_p[4][NKV];
    __shared__ int   sh_voff[4][NKV];

    const size_t bq = (size_t)b * S2V + qi;

    // stage q (pre-scaled) and index offsets
    const float* qrow = q + (bq * NHV + n) * HV;
    sh_q[w][lane] = qrow[lane] * 0.125f;   // h^-0.5 = 1/8
    const int my_idx = idx[bq * NKV + lane];
    const int my_off = my_idx * (NHV * HV);   // element offset of row
    sh_voff[w][lane] = my_off;
    __syncthreads();

    // ---- phase 1: scores (lane = key slot) ----
    const float* kb   = k + ((size_t)b * SS * NHV + n) * HV;
    const float* krow = kb + my_off;
    float acc = 0.f;
#pragma unroll
    for (int hc = 0; hc < HV / 4; ++hc) {
        const float4 k4 = *(const float4*)(krow + hc * 4);
        const float4 q4 = *(const float4*)(&sh_q[w][hc * 4]);
        acc = fmaf(k4.x, q4.x, acc);
        acc = fmaf(k4.y, q4.y, acc);
        acc = fmaf(k4.z, q4.z, acc);
        acc = fmaf(k4.w, q4.w, acc);
    }

    // ---- softmax over the 64 key slots (full wave) ----
    float m = acc;
#pragma unroll
    for (int off = 32; off > 0; off >>= 1) m = fmaxf(m, __shfl_xor(m, off));
    const float e = __expf(acc - m);
    float s = e;
#pragma unroll
    for (int off = 32; off > 0; off >>= 1) s += __shfl_xor(s, off);
    sh_p[w][lane] = e / s;
    __syncthreads();

    // ---- phase 2: output (lane = h) ----
    const float* vb = v + ((size_t)b * SS * NHV + n) * HV + lane;
    float z = 0.f;
#pragma unroll 8
    for (int ki = 0; ki < NKV; ++ki) {
        z = fmaf(sh_p[w][ki], vb[sh_voff[w][ki]], z);
    }
    out[(bq * NHV + n) * HV + lane] = z;
}

extern "C" void kernel_launch(void* const* d_in, const int* in_sizes, int n_in,
                              void* d_out, int out_size, void* d_ws, size_t ws_size,
                              hipStream_t stream) {
    const float* q   = (const float*)d_in[0];
    const float* k   = (const float*)d_in[1];
    const float* v   = (const float*)d_in[2];
    const int*   idx = (const int*)d_in[3];
    float*       out = (float*)d_out;

    const int n_units = BB * S2V * NHV;       // 32768 waves
    const int blocks  = n_units / 4;          // 8192 blocks of 4 waves
    rsa_kernel<<<blocks, 256, 0, stream>>>(q, k, v, idx, out);
}